// Round 16
// baseline (500.700 us; speedup 1.0000x reference)
//
#include <hip/hip_runtime.h>
#include <hip/hip_bf16.h>
#include <stdint.h>

typedef _Float16 F16;
typedef F16 f16x8 __attribute__((ext_vector_type(8)));
typedef F16 f16x4 __attribute__((ext_vector_type(4)));
typedef float f32x4 __attribute__((ext_vector_type(4)));

#define NTOK   16384   // BATCH*SEQLEN
#define DMODEL 1024
#define DINNER 2048
#define DSTATE 64
#define NHEADS 32
#define DINPRJ 4256
#define SEQLEN_ 4096
#define SEGLEN 128
#define NSEG   32

__device__ __forceinline__ void load_lds16(const void* g, void* l) {
  __builtin_amdgcn_global_load_lds((__attribute__((address_space(1))) void*)g,
                                   (__attribute__((address_space(3))) void*)l,
                                   16, 0, 0);
}

// XOR-swizzled LDS helpers (T2-style): byte ^= (row&7)<<4, bijective per row.
__device__ __forceinline__ void lds_st8(F16* base, int row, int col, int rowbytes, f16x8 v) {
  int by = (row * rowbytes + col * 2) ^ ((row & 7) << 4);
  *(f16x8*)((char*)base + by) = v;
}
__device__ __forceinline__ void lds_st1(F16* base, int row, int col, int rowbytes, F16 v) {
  int by = (row * rowbytes + col * 2) ^ ((row & 7) << 4);
  *(F16*)((char*)base + by) = v;
}
__device__ __forceinline__ f16x8 lds_ld8(const F16* base, int row, int col, int rowbytes) {
  int by = (row * rowbytes + col * 2) ^ ((row & 7) << 4);
  return *(const f16x8*)((const char*)base + by);
}

// ---------------- f32 -> f16 weight convert ----------------
__global__ __launch_bounds__(256) void cvt_kernel(const float* __restrict__ src,
                                                  F16* __restrict__ dst, int n4) {
  int i = blockIdx.x * 256 + threadIdx.x;
  if (i >= n4) return;
  float4 v = *(const float4*)(src + (size_t)i * 4);
  f16x4 o = { (F16)v.x, (F16)v.y, (F16)v.z, (F16)v.w };
  *(f16x4*)(dst + (size_t)i * 4) = o;
}

// ---------------- block reduce helper (256 thr) ----------------
__device__ __forceinline__ void blk_reduce2(float& s, float& ss) {
  __shared__ float red[8];
#pragma unroll
  for (int m = 32; m >= 1; m >>= 1) { s += __shfl_xor(s, m, 64); ss += __shfl_xor(ss, m, 64); }
  int tid = threadIdx.x, wv = tid >> 6;
  if ((tid & 63) == 0) { red[wv * 2] = s; red[wv * 2 + 1] = ss; }
  __syncthreads();
  s  = red[0] + red[2] + red[4] + red[6];
  ss = red[1] + red[3] + red[5] + red[7];
}

// ---------------- LN over x (1024) -> f16 ----------------
__global__ __launch_bounds__(256) void ln_in_kernel(const float* __restrict__ x,
                                                    const float* __restrict__ w,
                                                    const float* __restrict__ b,
                                                    F16* __restrict__ out) {
  int row = blockIdx.x, tid = threadIdx.x;
  const float* xr = x + (size_t)row * DMODEL + tid * 4;
  float4 v = *(const float4*)xr;
  float s = v.x + v.y + v.z + v.w;
  float ss = v.x * v.x + v.y * v.y + v.z * v.z + v.w * v.w;
  blk_reduce2(s, ss);
  float mu = s * (1.f / DMODEL);
  float var = ss * (1.f / DMODEL) - mu * mu;
  float rs = rsqrtf(var + 1e-5f);
  float4 wv = *(const float4*)(w + tid * 4);
  float4 bv = *(const float4*)(b + tid * 4);
  f16x4 o;
  o.x = (F16)((v.x - mu) * rs * wv.x + bv.x);
  o.y = (F16)((v.y - mu) * rs * wv.y + bv.y);
  o.z = (F16)((v.z - mu) * rs * wv.z + bv.z);
  o.w = (F16)((v.w - mu) * rs * wv.w + bv.w);
  *(f16x4*)(out + (size_t)row * DMODEL + tid * 4) = o;
}

// ---------------- f16 MFMA GEMM, out = A[M][K] @ W[N][K]^T ----------------
// r11 config + 5 blocks/CU (LDS 5x32KiB = exactly 160 KiB; VGPR 56 <= 102):
// 128x128 tile, BK=32, 4 waves, double-buffered LDS, counted vmcnt(4),
// swizzle chunk ^= (row>>1)&3 (conflict-free, r11-verified), XCD map r6.
// EPI 0: split zxbcdt epilogue (B/C f16); EPI 1: f16 store [*,1024]
template<int KD, int EPI>
__global__ __launch_bounds__(256, 5)
void gemm_kernel(const F16* __restrict__ A, const F16* __restrict__ W, int Nw,
                 F16* __restrict__ Z, F16* __restrict__ XS,
                 F16* __restrict__ BCH, float* __restrict__ DT,
                 F16* __restrict__ O1H)
{
  constexpr int NT = KD / 32;
  __shared__ __align__(16) F16 Ab[2][128 * 32];
  __shared__ __align__(16) F16 Bb[2][128 * 32];
  const int tid = threadIdx.x;
  const int lane = tid & 63;
  const int wid = tid >> 6;
  const int wm = wid >> 1, wn = wid & 1;
  const int id = blockIdx.x;
  const int bx = (id & 7) * 16 + ((id >> 3) & 15);
  const int by = id >> 7;
  const int m0 = bx * 128, n0 = by * 128;
  const int lr = lane & 15, lk = lane >> 4;

  f32x4 acc[4][4];
#pragma unroll
  for (int i = 0; i < 4; ++i)
#pragma unroll
    for (int j = 0; j < 4; ++j) acc[i][j] = f32x4{0.f, 0.f, 0.f, 0.f};

#define STAGE(T, BUF)                                                          \
  {                                                                            \
    const int k0s = (T) * 32;                                                  \
    _Pragma("unroll")                                                          \
    for (int i = 0; i < 2; ++i) {                                              \
      const int u = i * 256 + tid;                                             \
      const int row = u >> 2;                                                  \
      const int cl = (u & 3) ^ ((row >> 1) & 3);                               \
      load_lds16(A + (size_t)(m0 + row) * KD + k0s + cl * 8, &Ab[BUF][u * 8]); \
    }                                                                          \
    _Pragma("unroll")                                                          \
    for (int i = 0; i < 2; ++i) {                                              \
      const int u = i * 256 + tid;                                             \
      const int row = u >> 2;                                                  \
      const int cl = (u & 3) ^ ((row >> 1) & 3);                               \
      int wr = n0 + row; if (wr >= Nw) wr = Nw - 1;                            \
      load_lds16(W + (size_t)wr * KD + k0s + cl * 8, &Bb[BUF][u * 8]);         \
    }                                                                          \
  }

  STAGE(0, 0);
  for (int t = 0; t < NT; ++t) {
    const int d = t & 1;
    if (t + 1 < NT) {
      STAGE(t + 1, d ^ 1);                                // 4 loads in flight for t+1
      __builtin_amdgcn_sched_barrier(0);
      asm volatile("s_waitcnt vmcnt(4)" ::: "memory");    // tile t landed
    } else {
      __builtin_amdgcn_sched_barrier(0);
      asm volatile("s_waitcnt vmcnt(0)" ::: "memory");
    }
    __builtin_amdgcn_sched_barrier(0);
    __builtin_amdgcn_s_barrier();
    __builtin_amdgcn_sched_barrier(0);

    const F16* Ac = Ab[d];
    const F16* Bc = Bb[d];
    const int cs = (lk ^ ((lr >> 1) & 3)) * 8;
    f16x8 af[4], bfr[4];
#pragma unroll
    for (int m = 0; m < 4; ++m)
      af[m] = *(const f16x8*)&Ac[(wm * 64 + m * 16 + lr) * 32 + cs];
#pragma unroll
    for (int n = 0; n < 4; ++n)
      bfr[n] = *(const f16x8*)&Bc[(wn * 64 + n * 16 + lr) * 32 + cs];
#pragma unroll
    for (int m = 0; m < 4; ++m)
#pragma unroll
      for (int n = 0; n < 4; ++n)
        acc[m][n] = __builtin_amdgcn_mfma_f32_16x16x32_f16(af[m], bfr[n], acc[m][n], 0, 0, 0);
    __builtin_amdgcn_sched_barrier(0);
    __builtin_amdgcn_s_barrier();   // all waves done with buf[d] -> next STAGE may overwrite
    __builtin_amdgcn_sched_barrier(0);
  }
#undef STAGE

#pragma unroll
  for (int m = 0; m < 4; ++m) {
#pragma unroll
    for (int n = 0; n < 4; ++n) {
      int r0 = m0 + wm * 64 + m * 16 + lk * 4;
      int c  = n0 + wn * 64 + n * 16 + lr;
#pragma unroll
      for (int j = 0; j < 4; ++j) {
        float v = acc[m][n][j];
        size_t r = (size_t)(r0 + j);
        if (EPI == 1) {
          O1H[r * 1024 + c] = (F16)v;
        } else {
          if (c < 2048)        Z[r * 2048 + c] = (F16)v;
          else if (c < 4096)   XS[r * 2048 + (c - 2048)] = (F16)v;
          else if (c < 4160)   BCH[r * 128 + (c - 4096)] = (F16)v;
          else if (c < 4224)   BCH[r * 128 + 64 + (c - 4160)] = (F16)v;
          else if (c < 4256)   DT[r * 32 + (c - 4224)] = v;
        }
      }
    }
  }
}

// ---------------- fused dt->log(dA) + in-segment cumsum ----------------
// grid (128 bh, 32 seg), 128 thr. LA[bh][seg*128+t]
__global__ __launch_bounds__(128) void la_kernel(const float* __restrict__ DT,
                                                 const float* __restrict__ dt_bias,
                                                 const float* __restrict__ A_log,
                                                 float* __restrict__ LA) {
  const int bh = blockIdx.x, seg = blockIdx.y;
  const int b = bh >> 5, h = bh & 31;
  const int t = threadIdx.x, lane = t & 63;
  size_t tok = (size_t)b * SEQLEN_ + (size_t)seg * SEGLEN + t;
  float vraw = DT[tok * 32 + h] + dt_bias[h];
  float sp = (vraw > 20.f) ? vraw : log1pf(expf(vraw));
  float dt = fminf(fmaxf(sp, 0.001f), 0.1f);
  float v = fminf(dt * (-expf(A_log[h])), -0.01005034f);   // log dA
#pragma unroll
  for (int m = 1; m <= 32; m <<= 1) {
    float o = __shfl_up(v, m, 64);
    if (lane >= m) v += o;
  }
  __shared__ float w0tot;
  if (t == 63) w0tot = v;
  __syncthreads();
  if (t >= 64) v += w0tot;
  LA[(size_t)bh * SEQLEN_ + (size_t)seg * SEGLEN + t] = v;
}

// ---------------- SSD chunk kernel: y_loc + h_loc via MFMA ----------------
// grid (32 h, 32 seg, 4 b), 256 thr = 4 waves. LDS 48 KB -> 3 blocks/CU:
// Mm (32 KB) OVERLAYS Cb|Bb (dead after G-phase; extra sync added).
__global__ __launch_bounds__(256) void ssd_kernel(const F16* __restrict__ BCH,
                                                  const float* __restrict__ LA,
                                                  F16* __restrict__ XS,
                                                  const float* __restrict__ Dparam,
                                                  F16* __restrict__ HLOC) {
  __shared__ __align__(16) F16 U[128 * 128];   // Cb=U[0..8191], Bb=U[8192..16383]; Mm=U
  __shared__ __align__(16) F16 Xb[64 * 128];   // [p][s] (transposed)
  F16* Cb = U;
  F16* Bbuf = U + 8192;
  F16* Mm = U;
  const int h = blockIdx.x, seg = blockIdx.y, b = blockIdx.z;
  const int tid = threadIdx.x, lane = tid & 63, w = tid >> 6;
  const int lr = lane & 15, lk = lane >> 4;
  const int bh = b * 32 + h;
  const size_t tok0 = (size_t)b * SEQLEN_ + (size_t)seg * SEGLEN;
  const float* la = LA + (size_t)bh * SEQLEN_ + (size_t)seg * SEGLEN;

  // ---- stage Cb[t][n], Bb[s][n] from BCH (f16 direct) ----
  {
    const int t = tid >> 1, half = tid & 1;
    const F16* srcB = BCH + (tok0 + t) * 128 + half * 32;
    const F16* srcC = srcB + 64;
#pragma unroll
    for (int i = 0; i < 4; ++i) {
      lds_st8(Bbuf, t, half * 32 + i * 8, 128, *(const f16x8*)(srcB + i * 8));
      lds_st8(Cb, t, half * 32 + i * 8, 128, *(const f16x8*)(srcC + i * 8));
    }
  }
  // ---- stage Xb[p][s] (transpose of XS chunk) ----
#pragma unroll
  for (int pass = 0; pass < 4; ++pass) {
    const int srel = tid & 31, oct = tid >> 5;
    const int s = pass * 32 + srel;
    f16x8 xv = *(const f16x8*)(XS + (tok0 + s) * 2048 + h * 64 + oct * 8);
#pragma unroll
    for (int i = 0; i < 8; ++i)
      lds_st1(Xb, oct * 8 + i, s, 256, xv[i]);
  }
  __syncthreads();

  // ---- G = C.B^T : D[t][s], wave owns t in [w*32, w*32+32) ----
  f32x4 g[2][8];
#pragma unroll
  for (int m = 0; m < 2; ++m)
#pragma unroll
    for (int n = 0; n < 8; ++n) g[m][n] = f32x4{0.f, 0.f, 0.f, 0.f};
#pragma unroll
  for (int kk = 0; kk < 2; ++kk) {
    f16x8 a0 = lds_ld8(Cb, w * 32 + lr,      kk * 32 + lk * 8, 128);
    f16x8 a1 = lds_ld8(Cb, w * 32 + 16 + lr, kk * 32 + lk * 8, 128);
#pragma unroll
    for (int n = 0; n < 8; ++n) {
      f16x8 bq = lds_ld8(Bbuf, n * 16 + lr, kk * 32 + lk * 8, 128);
      g[0][n] = __builtin_amdgcn_mfma_f32_16x16x32_f16(a0, bq, g[0][n], 0, 0, 0);
      g[1][n] = __builtin_amdgcn_mfma_f32_16x16x32_f16(a1, bq, g[1][n], 0, 0, 0);
    }
  }
  __syncthreads();   // Cb/Bb dead; Mm may now overwrite them

  // ---- M[t][s] = (s<=t) ? G*exp(la[t]-la[s]) : 0 ; M[t][t] += Dh ----
  const float Dh = Dparam[h];
  float lat[2][4];
#pragma unroll
  for (int m = 0; m < 2; ++m)
#pragma unroll
    for (int j = 0; j < 4; ++j)
      lat[m][j] = la[w * 32 + m * 16 + lk * 4 + j];
#pragma unroll
  for (int n = 0; n < 8; ++n) {
    const int s = n * 16 + lr;
    const float las = la[s];
#pragma unroll
    for (int m = 0; m < 2; ++m)
#pragma unroll
      for (int j = 0; j < 4; ++j) {
        const int t = w * 32 + m * 16 + lk * 4 + j;
        float v = (s <= t) ? g[m][n][j] * __expf(lat[m][j] - las) : 0.f;
        if (s == t) v += Dh;
        lds_st1(Mm, t, s, 256, (F16)v);
      }
  }
  __syncthreads();

  // ---- Y = M.X : D[t][p] -> overwrite XS (y_loc incl. D-residual) ----
  f32x4 y[2][4];
#pragma unroll
  for (int m = 0; m < 2; ++m)
#pragma unroll
    for (int n = 0; n < 4; ++n) y[m][n] = f32x4{0.f, 0.f, 0.f, 0.f};
#pragma unroll
  for (int kk = 0; kk < 4; ++kk) {
    f16x8 a0 = lds_ld8(Mm, w * 32 + lr,      kk * 32 + lk * 8, 256);
    f16x8 a1 = lds_ld8(Mm, w * 32 + 16 + lr, kk * 32 + lk * 8, 256);
#pragma unroll
    for (int n = 0; n < 4; ++n) {
      f16x8 bq = lds_ld8(Xb, n * 16 + lr, kk * 32 + lk * 8, 256);
      y[0][n] = __builtin_amdgcn_mfma_f32_16x16x32_f16(a0, bq, y[0][n], 0, 0, 0);
      y[1][n] = __builtin_amdgcn_mfma_f32_16x16x32_f16(a1, bq, y[1][n], 0, 0, 0);
    }
  }
#pragma unroll
  for (int m = 0; m < 2; ++m)
#pragma unroll
    for (int n = 0; n < 4; ++n)
#pragma unroll
      for (int j = 0; j < 4; ++j) {
        const int t = w * 32 + m * 16 + lk * 4 + j;
        const int p = n * 16 + lr;
        XS[(tok0 + t) * 2048 + h * 64 + p] = (F16)y[m][n][j];
      }
  __syncthreads();

  // ---- stage Bdt[n][s] = B[s][n]*exp(la[127]-la[s]) into Mm region ----
  {
    const int s = tid >> 1, half = tid & 1;
    const float dec = __expf(la[127] - la[s]);
    const F16* srcB = BCH + (tok0 + s) * 128 + half * 32;
#pragma unroll
    for (int i = 0; i < 4; ++i) {
      f16x8 bv = *(const f16x8*)(srcB + i * 8);
#pragma unroll
      for (int q = 0; q < 8; ++q)
        lds_st1(Mm, half * 32 + i * 8 + q, s, 256, (F16)((float)bv[q] * dec));
    }
  }
  __syncthreads();

  // ---- H = X.Bdt^T : D[p][n], wave owns p in [w*16, w*16+16) ----
  f32x4 hh[4];
#pragma unroll
  for (int n = 0; n < 4; ++n) hh[n] = f32x4{0.f, 0.f, 0.f, 0.f};
#pragma unroll
  for (int kk = 0; kk < 4; ++kk) {
    f16x8 a = lds_ld8(Xb, w * 16 + lr, kk * 32 + lk * 8, 256);
#pragma unroll
    for (int n = 0; n < 4; ++n) {
      f16x8 bq = lds_ld8(Mm, n * 16 + lr, kk * 32 + lk * 8, 256);
      hh[n] = __builtin_amdgcn_mfma_f32_16x16x32_f16(a, bq, hh[n], 0, 0, 0);
    }
  }
  F16* dst = HLOC + ((size_t)bh * NSEG + seg) * 4096;
#pragma unroll
  for (int n = 0; n < 4; ++n)
#pragma unroll
    for (int j = 0; j < 4; ++j) {
      const int p = w * 16 + lk * 4 + j;
      dst[p * 64 + n * 16 + lr] = (F16)hh[n][j];
    }
}

// ---------------- combine across segments (h_bnd over h_loc, in place) ----
__global__ __launch_bounds__(256) void combine_kernel(F16* __restrict__ HLOC,
                                                      const float* __restrict__ LA) {
  const int bh = blockIdx.x, tid = threadIdx.x;
  const int p = tid >> 2, n0 = (tid & 3) * 16;
  F16* base = HLOC + (size_t)bh * NSEG * 4096 + p * 64 + n0;
  const float* la = LA + (size_t)bh * SEQLEN_;
  union U16 { uint4 v[2]; F16 h[16]; };
  float r[16];
#pragma unroll
  for (int i = 0; i < 16; ++i) r[i] = 0.f;
  for (int k = 0; k < NSEG; ++k) {
    F16* slot = base + (size_t)k * 4096;
    U16 hl; hl.v[0] = *(const uint4*)slot; hl.v[1] = *((const uint4*)slot + 1);
    float P = __expf(la[k * SEGLEN + SEGLEN - 1]);
    U16 ob;
#pragma unroll
    for (int i = 0; i < 16; ++i) ob.h[i] = (F16)r[i];
    *(uint4*)slot = ob.v[0]; *((uint4*)slot + 1) = ob.v[1];   // h_bnd[k]
#pragma unroll
    for (int i = 0; i < 16; ++i) r[i] = fmaf(P, r[i], (float)hl.h[i]);
  }
}

// ---------------- boundary correction: y[t,p] += exp(la[t]) * C[t].h_bnd ----
__global__ __launch_bounds__(256) void corr_kernel(const F16* __restrict__ BCH,
                                                   const float* __restrict__ LA,
                                                   const F16* __restrict__ HLOC,
                                                   F16* __restrict__ XS) {
  __shared__ __align__(16) F16 Cd[128 * 72];
  __shared__ __align__(16) F16 Hb[64 * 72];
  const int seg = blockIdx.x, h = blockIdx.y, b = blockIdx.z;
  const int tid = threadIdx.x;
  const size_t tok0 = (size_t)b * SEQLEN_ + (size_t)seg * SEGLEN;
  const int bh = b * 32 + h;
  {
    int t = tid >> 1, half = tid & 1;
    float Dv = __expf(LA[(size_t)bh * SEQLEN_ + seg * SEGLEN + t]);
    const F16* src = BCH + (tok0 + t) * 128 + 64 + half * 32;
    F16* dstp = &Cd[t * 72 + half * 32];
#pragma unroll
    for (int i = 0; i < 4; ++i) {
      f16x8 cv = *(const f16x8*)(src + i * 8);
      f16x8 o;
#pragma unroll
      for (int q = 0; q < 8; ++q) o[q] = (F16)(Dv * (float)cv[q]);
      *(f16x8*)(dstp + i * 8) = o;
    }
  }
  {
    int p = tid >> 2, nn = (tid & 3) * 16;
    const F16* src = HLOC + ((size_t)bh * NSEG + seg) * 4096 + p * 64 + nn;
    uint4 a0 = *(const uint4*)src, a1 = *((const uint4*)src + 1);
    *(uint4*)&Hb[p * 72 + nn] = a0;
    *(uint4*)&Hb[p * 72 + nn + 8] = a1;
  }
  __syncthreads();
  const int lane = tid & 63, w = tid >> 6;
  const int lr = lane & 15, lk = lane >> 4;
  f32x4 acc[2][4];
#pragma unroll
  for (int m = 0; m < 2; ++m)
#pragma unroll
    for (int n = 0; n < 4; ++n) acc[m][n] = f32x4{0.f, 0.f, 0.f, 0.f};
#pragma unroll
  for (int kk = 0; kk < 2; ++kk) {
    f16x8 a0 = *(const f16x8*)&Cd[(w * 32 + lr) * 72 + kk * 32 + lk * 8];
    f16x8 a1 = *(const f16x8*)&Cd[(w * 32 + 16 + lr) * 72 + kk * 32 + lk * 8];
#pragma unroll
    for (int n = 0; n < 4; ++n) {
      f16x8 bq = *(const f16x8*)&Hb[(n * 16 + lr) * 72 + kk * 32 + lk * 8];
      acc[0][n] = __builtin_amdgcn_mfma_f32_16x16x32_f16(a0, bq, acc[0][n], 0, 0, 0);
      acc[1][n] = __builtin_amdgcn_mfma_f32_16x16x32_f16(a1, bq, acc[1][n], 0, 0, 0);
    }
  }
#pragma unroll
  for (int m = 0; m < 2; ++m)
#pragma unroll
    for (int n = 0; n < 4; ++n)
#pragma unroll
      for (int j = 0; j < 4; ++j) {
        int t = w * 32 + m * 16 + lk * 4 + j;
        int p = n * 16 + lr;
        F16* yp = XS + (tok0 + t) * 2048 + h * 64 + p;
        *yp = (F16)((float)*yp + acc[m][n][j]);
      }
}

// ---------------- y * silu(z) -> LN (2048) -> f16, in-place over Y ----------------
__global__ __launch_bounds__(256) void silu_ln_kernel(F16* __restrict__ Y,
                                                      const F16* __restrict__ Z,
                                                      const float* __restrict__ lnw,
                                                      const float* __restrict__ lnb) {
  int row = blockIdx.x, tid = threadIdx.x;
  size_t base = (size_t)row * DINNER + tid * 8;
  union { uint4 v; F16 h[8]; } yb, zb, ob;
  yb.v = *(const uint4*)(Y + base);
  zb.v = *(const uint4*)(Z + base);
  float vv[8];
  float s = 0.f, ss = 0.f;
#pragma unroll
  for (int i = 0; i < 8; ++i) {
    float y = (float)yb.h[i];
    float z = (float)zb.h[i];
    float sg = 1.f / (1.f + expf(-z));
    float v = y * z * sg;
    vv[i] = v; s += v; ss += v * v;
  }
  blk_reduce2(s, ss);
  float mu = s * (1.f / DINNER);
  float var = ss * (1.f / DINNER) - mu * mu;
  float rs = rsqrtf(var + 1e-5f);
#pragma unroll
  for (int i = 0; i < 8; ++i) {
    float w = lnw[tid * 8 + i], b = lnb[tid * 8 + i];
    ob.h[i] = (F16)((vv[i] - mu) * rs * w + b);
  }
  *(uint4*)(Y + base) = ob.v;
}

// ---------------- clip + final LN (1024): O1H f16 in -> f32 d_out ----------------
__global__ __launch_bounds__(256) void final_ln_kernel(const F16* __restrict__ O1H,
                                                       const float* __restrict__ w,
                                                       const float* __restrict__ b,
                                                       float* __restrict__ out) {
  int row = blockIdx.x, tid = threadIdx.x;
  size_t base = (size_t)row * DMODEL + tid * 4;
  f16x4 hv = *(const f16x4*)(O1H + base);
  float4 v = { (float)hv.x, (float)hv.y, (float)hv.z, (float)hv.w };
  v.x = fminf(fmaxf(v.x, -10.f), 10.f);
  v.y = fminf(fmaxf(v.y, -10.f), 10.f);
  v.z = fminf(fmaxf(v.z, -10.f), 10.f);
  v.w = fminf(fmaxf(v.w, -10.f), 10.f);
  float s = v.x + v.y + v.z + v.w;
  float ss = v.x * v.x + v.y * v.y + v.z * v.z + v.w * v.w;
  blk_reduce2(s, ss);
  float mu = s * (1.f / DMODEL);
  float var = ss * (1.f / DMODEL) - mu * mu;
  float rs = rsqrtf(var + 1e-5f);
  float4 wv = *(const float4*)(w + tid * 4);
  float4 bv = *(const float4*)(b + tid * 4);
  float4 o;
  o.x = (v.x - mu) * rs * wv.x + bv.x;
  o.y = (v.y - mu) * rs * wv.y + bv.y;
  o.z = (v.z - mu) * rs * wv.z + bv.z;
  o.w = (v.w - mu) * rs * wv.w + bv.w;
  *(float4*)(out + base) = o;
}

// ---------------- launcher ----------------
// Workspace high-water 117,440,512 B < proven-safe 119,865,344. Aliasing:
//   Z->d_out; y->XS in place; W2F->XN head; HLOC/LA->dead XN/W1F tail;
//   O1H (f16 gemm2 out) -> HLOC region (dead after corr). BCH (f16 B|C).
extern "C" void kernel_launch(void* const* d_in, const int* in_sizes, int n_in,
                              void* d_out, int out_size, void* d_ws, size_t ws_size,
                              hipStream_t stream) {
  const float* x       = (const float*)d_in[0];
  const float* w1      = (const float*)d_in[1];
  const float* w2      = (const float*)d_in[2];
  const float* A_log   = (const float*)d_in[3];
  const float* dt_bias = (const float*)d_in[4];
  const float* Dparam  = (const float*)d_in[5];
  const float* ln_w    = (const float*)d_in[6];
  const float* ln_b    = (const float*)d_in[7];
  const float* ni_w    = (const float*)d_in[8];
  const float* ni_b    = (const float*)d_in[9];
  const float* no_w    = (const float*)d_in[10];
  const float* no_b    = (const float*)d_in[11];

  const size_t NEEDED = 119865344ull;
  if (ws_size < NEEDED) return;

  char* wsb = (char*)d_ws;
  F16*   XS   = (F16*)  (wsb + 0ull);           // 16384x2048 f16 (x_ssm -> y -> y_gn)
  F16*   BCH  = (F16*)  (wsb + 67108864ull);    // 16384x128 f16 (B|C)
  float* DT   = (float*)(wsb + 75497472ull);    // 16384x32 f32 (raw dt)
  F16*   XN   = (F16*)  (wsb + 77594624ull);    // 16384x1024 f16 (dead after gemm1)
  F16*   W2F  = (F16*)  (wsb + 77594624ull);    // 1024x2048 f16 (reuses XN head)
  F16*   HLOC = (F16*)  (wsb + 81788928ull);    // 128x32x64x64 f16 = 32 MiB
  F16*   O1H  = (F16*)  (wsb + 81788928ull);    // 16384x1024 f16 (reuses HLOC after corr)
  float* LA   = (float*)(wsb + 115343360ull);   // 128x4096 f32 = 2 MiB
  F16*   W1F  = (F16*)  (wsb + 111149056ull);   // 4256x1024 f16 (dead after gemm1;
                                                // overlaps HLOC/LA tail — safe by ordering)

  F16*   Z   = (F16*)d_out;                     // 16384x2048 f16 in d_out (until silu_ln)

  cvt_kernel<<<4256, 256, 0, stream>>>(w1, W1F, (DINPRJ * DMODEL) / 4);
  ln_in_kernel<<<NTOK, 256, 0, stream>>>(x, ni_w, ni_b, XN);
  gemm_kernel<1024, 0><<<128 * 34, 256, 0, stream>>>(
      XN, W1F, DINPRJ, Z, XS, BCH, DT, nullptr);
  cvt_kernel<<<2048, 256, 0, stream>>>(w2, W2F, (DMODEL * DINNER) / 4);
  la_kernel<<<dim3(128, NSEG), 128, 0, stream>>>(DT, dt_bias, A_log, LA);
  ssd_kernel<<<dim3(32, NSEG, 4), 256, 0, stream>>>(BCH, LA, XS, Dparam, HLOC);
  combine_kernel<<<128, 256, 0, stream>>>(HLOC, LA);
  corr_kernel<<<dim3(NSEG, 32, 4), 256, 0, stream>>>(BCH, LA, HLOC, XS);
  silu_ln_kernel<<<NTOK, 256, 0, stream>>>(XS, Z, ln_w, ln_b);
  gemm_kernel<2048, 1><<<128 * 8, 256, 0, stream>>>(
      XS, W2F, 1024, nullptr, nullptr, nullptr, nullptr, O1H);
  final_ln_kernel<<<NTOK, 256, 0, stream>>>(O1H, no_w, no_b, (float*)d_out);
}

// Round 17
// 482.178 us; speedup vs baseline: 1.0384x; 1.0384x over previous
//
#include <hip/hip_runtime.h>
#include <hip/hip_bf16.h>
#include <stdint.h>

typedef _Float16 F16;
typedef F16 f16x8 __attribute__((ext_vector_type(8)));
typedef F16 f16x4 __attribute__((ext_vector_type(4)));
typedef float f32x4 __attribute__((ext_vector_type(4)));

#define NTOK   16384   // BATCH*SEQLEN
#define DMODEL 1024
#define DINNER 2048
#define DSTATE 64
#define NHEADS 32
#define DINPRJ 4256
#define SEQLEN_ 4096
#define SEGLEN 128
#define NSEG   32

__device__ __forceinline__ void load_lds16(const void* g, void* l) {
  __builtin_amdgcn_global_load_lds((__attribute__((address_space(1))) void*)g,
                                   (__attribute__((address_space(3))) void*)l,
                                   16, 0, 0);
}

// XOR-swizzled LDS helpers (T2-style): byte ^= (row&7)<<4, bijective per row.
__device__ __forceinline__ void lds_st8(F16* base, int row, int col, int rowbytes, f16x8 v) {
  int by = (row * rowbytes + col * 2) ^ ((row & 7) << 4);
  *(f16x8*)((char*)base + by) = v;
}
__device__ __forceinline__ void lds_st1(F16* base, int row, int col, int rowbytes, F16 v) {
  int by = (row * rowbytes + col * 2) ^ ((row & 7) << 4);
  *(F16*)((char*)base + by) = v;
}
__device__ __forceinline__ f16x8 lds_ld8(const F16* base, int row, int col, int rowbytes) {
  int by = (row * rowbytes + col * 2) ^ ((row & 7) << 4);
  return *(const f16x8*)((const char*)base + by);
}

// ---------------- f32 -> f16 weight convert ----------------
__global__ __launch_bounds__(256) void cvt_kernel(const float* __restrict__ src,
                                                  F16* __restrict__ dst, int n4) {
  int i = blockIdx.x * 256 + threadIdx.x;
  if (i >= n4) return;
  float4 v = *(const float4*)(src + (size_t)i * 4);
  f16x4 o = { (F16)v.x, (F16)v.y, (F16)v.z, (F16)v.w };
  *(f16x4*)(dst + (size_t)i * 4) = o;
}

// ---------------- block reduce helper (256 thr) ----------------
__device__ __forceinline__ void blk_reduce2(float& s, float& ss) {
  __shared__ float red[8];
#pragma unroll
  for (int m = 32; m >= 1; m >>= 1) { s += __shfl_xor(s, m, 64); ss += __shfl_xor(ss, m, 64); }
  int tid = threadIdx.x, wv = tid >> 6;
  if ((tid & 63) == 0) { red[wv * 2] = s; red[wv * 2 + 1] = ss; }
  __syncthreads();
  s  = red[0] + red[2] + red[4] + red[6];
  ss = red[1] + red[3] + red[5] + red[7];
}

// ---------------- LN over x (1024) -> f16 ----------------
__global__ __launch_bounds__(256) void ln_in_kernel(const float* __restrict__ x,
                                                    const float* __restrict__ w,
                                                    const float* __restrict__ b,
                                                    F16* __restrict__ out) {
  int row = blockIdx.x, tid = threadIdx.x;
  const float* xr = x + (size_t)row * DMODEL + tid * 4;
  float4 v = *(const float4*)xr;
  float s = v.x + v.y + v.z + v.w;
  float ss = v.x * v.x + v.y * v.y + v.z * v.z + v.w * v.w;
  blk_reduce2(s, ss);
  float mu = s * (1.f / DMODEL);
  float var = ss * (1.f / DMODEL) - mu * mu;
  float rs = rsqrtf(var + 1e-5f);
  float4 wv = *(const float4*)(w + tid * 4);
  float4 bv = *(const float4*)(b + tid * 4);
  f16x4 o;
  o.x = (F16)((v.x - mu) * rs * wv.x + bv.x);
  o.y = (F16)((v.y - mu) * rs * wv.y + bv.y);
  o.z = (F16)((v.z - mu) * rs * wv.z + bv.z);
  o.w = (F16)((v.w - mu) * rs * wv.w + bv.w);
  *(f16x4*)(out + (size_t)row * DMODEL + tid * 4) = o;
}

// ---------------- f16 MFMA GEMM, out = A[M][K] @ W[N][K]^T ----------------
// r11/r15 config (best measured): 128x128 tile, BK=32, 4 waves,
// double-buffered LDS (32 KiB -> 4 blocks/CU), counted vmcnt(4) pipeline,
// swizzle chunk ^= (row>>1)&3 (conflict-free, r11-verified), XCD map r6.
// EPI 0: split zxbcdt epilogue (B/C f16); EPI 1: f16 store [*,1024]
template<int KD, int EPI>
__global__ __launch_bounds__(256, 4)
void gemm_kernel(const F16* __restrict__ A, const F16* __restrict__ W, int Nw,
                 F16* __restrict__ Z, F16* __restrict__ XS,
                 F16* __restrict__ BCH, float* __restrict__ DT,
                 F16* __restrict__ O1H)
{
  constexpr int NT = KD / 32;
  __shared__ __align__(16) F16 Ab[2][128 * 32];
  __shared__ __align__(16) F16 Bb[2][128 * 32];
  const int tid = threadIdx.x;
  const int lane = tid & 63;
  const int wid = tid >> 6;
  const int wm = wid >> 1, wn = wid & 1;
  const int id = blockIdx.x;
  const int bx = (id & 7) * 16 + ((id >> 3) & 15);
  const int by = id >> 7;
  const int m0 = bx * 128, n0 = by * 128;
  const int lr = lane & 15, lk = lane >> 4;

  f32x4 acc[4][4];
#pragma unroll
  for (int i = 0; i < 4; ++i)
#pragma unroll
    for (int j = 0; j < 4; ++j) acc[i][j] = f32x4{0.f, 0.f, 0.f, 0.f};

#define STAGE(T, BUF)                                                          \
  {                                                                            \
    const int k0s = (T) * 32;                                                  \
    _Pragma("unroll")                                                          \
    for (int i = 0; i < 2; ++i) {                                              \
      const int u = i * 256 + tid;                                             \
      const int row = u >> 2;                                                  \
      const int cl = (u & 3) ^ ((row >> 1) & 3);                               \
      load_lds16(A + (size_t)(m0 + row) * KD + k0s + cl * 8, &Ab[BUF][u * 8]); \
    }                                                                          \
    _Pragma("unroll")                                                          \
    for (int i = 0; i < 2; ++i) {                                              \
      const int u = i * 256 + tid;                                             \
      const int row = u >> 2;                                                  \
      const int cl = (u & 3) ^ ((row >> 1) & 3);                               \
      int wr = n0 + row; if (wr >= Nw) wr = Nw - 1;                            \
      load_lds16(W + (size_t)wr * KD + k0s + cl * 8, &Bb[BUF][u * 8]);         \
    }                                                                          \
  }

  STAGE(0, 0);
  for (int t = 0; t < NT; ++t) {
    const int d = t & 1;
    if (t + 1 < NT) {
      STAGE(t + 1, d ^ 1);                                // 4 loads in flight for t+1
      __builtin_amdgcn_sched_barrier(0);
      asm volatile("s_waitcnt vmcnt(4)" ::: "memory");    // tile t landed
    } else {
      __builtin_amdgcn_sched_barrier(0);
      asm volatile("s_waitcnt vmcnt(0)" ::: "memory");
    }
    __builtin_amdgcn_sched_barrier(0);
    __builtin_amdgcn_s_barrier();
    __builtin_amdgcn_sched_barrier(0);

    const F16* Ac = Ab[d];
    const F16* Bc = Bb[d];
    const int cs = (lk ^ ((lr >> 1) & 3)) * 8;
    f16x8 af[4], bfr[4];
#pragma unroll
    for (int m = 0; m < 4; ++m)
      af[m] = *(const f16x8*)&Ac[(wm * 64 + m * 16 + lr) * 32 + cs];
#pragma unroll
    for (int n = 0; n < 4; ++n)
      bfr[n] = *(const f16x8*)&Bc[(wn * 64 + n * 16 + lr) * 32 + cs];
#pragma unroll
    for (int m = 0; m < 4; ++m)
#pragma unroll
      for (int n = 0; n < 4; ++n)
        acc[m][n] = __builtin_amdgcn_mfma_f32_16x16x32_f16(af[m], bfr[n], acc[m][n], 0, 0, 0);
    __builtin_amdgcn_sched_barrier(0);
    __builtin_amdgcn_s_barrier();   // all waves done with buf[d] -> next STAGE may overwrite
    __builtin_amdgcn_sched_barrier(0);
  }
#undef STAGE

#pragma unroll
  for (int m = 0; m < 4; ++m) {
#pragma unroll
    for (int n = 0; n < 4; ++n) {
      int r0 = m0 + wm * 64 + m * 16 + lk * 4;
      int c  = n0 + wn * 64 + n * 16 + lr;
#pragma unroll
      for (int j = 0; j < 4; ++j) {
        float v = acc[m][n][j];
        size_t r = (size_t)(r0 + j);
        if (EPI == 1) {
          O1H[r * 1024 + c] = (F16)v;
        } else {
          if (c < 2048)        Z[r * 2048 + c] = (F16)v;
          else if (c < 4096)   XS[r * 2048 + (c - 2048)] = (F16)v;
          else if (c < 4160)   BCH[r * 128 + (c - 4096)] = (F16)v;
          else if (c < 4224)   BCH[r * 128 + 64 + (c - 4160)] = (F16)v;
          else if (c < 4256)   DT[r * 32 + (c - 4224)] = v;
        }
      }
    }
  }
}

// ---------------- fused dt->log(dA) + in-segment cumsum ----------------
// grid (128 bh, 32 seg), 128 thr. LA[bh][seg*128+t]
__global__ __launch_bounds__(128) void la_kernel(const float* __restrict__ DT,
                                                 const float* __restrict__ dt_bias,
                                                 const float* __restrict__ A_log,
                                                 float* __restrict__ LA) {
  const int bh = blockIdx.x, seg = blockIdx.y;
  const int b = bh >> 5, h = bh & 31;
  const int t = threadIdx.x, lane = t & 63;
  size_t tok = (size_t)b * SEQLEN_ + (size_t)seg * SEGLEN + t;
  float vraw = DT[tok * 32 + h] + dt_bias[h];
  float sp = (vraw > 20.f) ? vraw : log1pf(expf(vraw));
  float dt = fminf(fmaxf(sp, 0.001f), 0.1f);
  float v = fminf(dt * (-expf(A_log[h])), -0.01005034f);   // log dA
#pragma unroll
  for (int m = 1; m <= 32; m <<= 1) {
    float o = __shfl_up(v, m, 64);
    if (lane >= m) v += o;
  }
  __shared__ float w0tot;
  if (t == 63) w0tot = v;
  __syncthreads();
  if (t >= 64) v += w0tot;
  LA[(size_t)bh * SEQLEN_ + (size_t)seg * SEGLEN + t] = v;
}

// ---------------- SSD chunk kernel: y_loc + h_loc via MFMA ----------------
// grid (32 h, 32 seg, 4 b), 256 thr = 4 waves. LDS 48 KB -> 3 blocks/CU:
// Mm (32 KB) OVERLAYS Cb|Bb (dead after G-phase; extra sync added).
__global__ __launch_bounds__(256) void ssd_kernel(const F16* __restrict__ BCH,
                                                  const float* __restrict__ LA,
                                                  F16* __restrict__ XS,
                                                  const float* __restrict__ Dparam,
                                                  F16* __restrict__ HLOC) {
  __shared__ __align__(16) F16 U[128 * 128];   // Cb=U[0..8191], Bb=U[8192..16383]; Mm=U
  __shared__ __align__(16) F16 Xb[64 * 128];   // [p][s] (transposed)
  F16* Cb = U;
  F16* Bbuf = U + 8192;
  F16* Mm = U;
  const int h = blockIdx.x, seg = blockIdx.y, b = blockIdx.z;
  const int tid = threadIdx.x, lane = tid & 63, w = tid >> 6;
  const int lr = lane & 15, lk = lane >> 4;
  const int bh = b * 32 + h;
  const size_t tok0 = (size_t)b * SEQLEN_ + (size_t)seg * SEGLEN;
  const float* la = LA + (size_t)bh * SEQLEN_ + (size_t)seg * SEGLEN;

  // ---- stage Cb[t][n], Bb[s][n] from BCH (f16 direct) ----
  {
    const int t = tid >> 1, half = tid & 1;
    const F16* srcB = BCH + (tok0 + t) * 128 + half * 32;
    const F16* srcC = srcB + 64;
#pragma unroll
    for (int i = 0; i < 4; ++i) {
      lds_st8(Bbuf, t, half * 32 + i * 8, 128, *(const f16x8*)(srcB + i * 8));
      lds_st8(Cb, t, half * 32 + i * 8, 128, *(const f16x8*)(srcC + i * 8));
    }
  }
  // ---- stage Xb[p][s] (transpose of XS chunk) ----
#pragma unroll
  for (int pass = 0; pass < 4; ++pass) {
    const int srel = tid & 31, oct = tid >> 5;
    const int s = pass * 32 + srel;
    f16x8 xv = *(const f16x8*)(XS + (tok0 + s) * 2048 + h * 64 + oct * 8);
#pragma unroll
    for (int i = 0; i < 8; ++i)
      lds_st1(Xb, oct * 8 + i, s, 256, xv[i]);
  }
  __syncthreads();

  // ---- G = C.B^T : D[t][s], wave owns t in [w*32, w*32+32) ----
  f32x4 g[2][8];
#pragma unroll
  for (int m = 0; m < 2; ++m)
#pragma unroll
    for (int n = 0; n < 8; ++n) g[m][n] = f32x4{0.f, 0.f, 0.f, 0.f};
#pragma unroll
  for (int kk = 0; kk < 2; ++kk) {
    f16x8 a0 = lds_ld8(Cb, w * 32 + lr,      kk * 32 + lk * 8, 128);
    f16x8 a1 = lds_ld8(Cb, w * 32 + 16 + lr, kk * 32 + lk * 8, 128);
#pragma unroll
    for (int n = 0; n < 8; ++n) {
      f16x8 bq = lds_ld8(Bbuf, n * 16 + lr, kk * 32 + lk * 8, 128);
      g[0][n] = __builtin_amdgcn_mfma_f32_16x16x32_f16(a0, bq, g[0][n], 0, 0, 0);
      g[1][n] = __builtin_amdgcn_mfma_f32_16x16x32_f16(a1, bq, g[1][n], 0, 0, 0);
    }
  }
  __syncthreads();   // Cb/Bb dead; Mm may now overwrite them

  // ---- M[t][s] = (s<=t) ? G*exp(la[t]-la[s]) : 0 ; M[t][t] += Dh ----
  const float Dh = Dparam[h];
  float lat[2][4];
#pragma unroll
  for (int m = 0; m < 2; ++m)
#pragma unroll
    for (int j = 0; j < 4; ++j)
      lat[m][j] = la[w * 32 + m * 16 + lk * 4 + j];
#pragma unroll
  for (int n = 0; n < 8; ++n) {
    const int s = n * 16 + lr;
    const float las = la[s];
#pragma unroll
    for (int m = 0; m < 2; ++m)
#pragma unroll
      for (int j = 0; j < 4; ++j) {
        const int t = w * 32 + m * 16 + lk * 4 + j;
        float v = (s <= t) ? g[m][n][j] * __expf(lat[m][j] - las) : 0.f;
        if (s == t) v += Dh;
        lds_st1(Mm, t, s, 256, (F16)v);
      }
  }
  __syncthreads();

  // ---- Y = M.X : D[t][p] -> overwrite XS (y_loc incl. D-residual) ----
  f32x4 y[2][4];
#pragma unroll
  for (int m = 0; m < 2; ++m)
#pragma unroll
    for (int n = 0; n < 4; ++n) y[m][n] = f32x4{0.f, 0.f, 0.f, 0.f};
#pragma unroll
  for (int kk = 0; kk < 4; ++kk) {
    f16x8 a0 = lds_ld8(Mm, w * 32 + lr,      kk * 32 + lk * 8, 256);
    f16x8 a1 = lds_ld8(Mm, w * 32 + 16 + lr, kk * 32 + lk * 8, 256);
#pragma unroll
    for (int n = 0; n < 4; ++n) {
      f16x8 bq = lds_ld8(Xb, n * 16 + lr, kk * 32 + lk * 8, 256);
      y[0][n] = __builtin_amdgcn_mfma_f32_16x16x32_f16(a0, bq, y[0][n], 0, 0, 0);
      y[1][n] = __builtin_amdgcn_mfma_f32_16x16x32_f16(a1, bq, y[1][n], 0, 0, 0);
    }
  }
#pragma unroll
  for (int m = 0; m < 2; ++m)
#pragma unroll
    for (int n = 0; n < 4; ++n)
#pragma unroll
      for (int j = 0; j < 4; ++j) {
        const int t = w * 32 + m * 16 + lk * 4 + j;
        const int p = n * 16 + lr;
        XS[(tok0 + t) * 2048 + h * 64 + p] = (F16)y[m][n][j];
      }
  __syncthreads();

  // ---- stage Bdt[n][s] = B[s][n]*exp(la[127]-la[s]) into Mm region ----
  {
    const int s = tid >> 1, half = tid & 1;
    const float dec = __expf(la[127] - la[s]);
    const F16* srcB = BCH + (tok0 + s) * 128 + half * 32;
#pragma unroll
    for (int i = 0; i < 4; ++i) {
      f16x8 bv = *(const f16x8*)(srcB + i * 8);
#pragma unroll
      for (int q = 0; q < 8; ++q)
        lds_st1(Mm, half * 32 + i * 8 + q, s, 256, (F16)((float)bv[q] * dec));
    }
  }
  __syncthreads();

  // ---- H = X.Bdt^T : D[p][n], wave owns p in [w*16, w*16+16) ----
  f32x4 hh[4];
#pragma unroll
  for (int n = 0; n < 4; ++n) hh[n] = f32x4{0.f, 0.f, 0.f, 0.f};
#pragma unroll
  for (int kk = 0; kk < 4; ++kk) {
    f16x8 a = lds_ld8(Xb, w * 16 + lr, kk * 32 + lk * 8, 256);
#pragma unroll
    for (int n = 0; n < 4; ++n) {
      f16x8 bq = lds_ld8(Mm, n * 16 + lr, kk * 32 + lk * 8, 256);
      hh[n] = __builtin_amdgcn_mfma_f32_16x16x32_f16(a, bq, hh[n], 0, 0, 0);
    }
  }
  F16* dst = HLOC + ((size_t)bh * NSEG + seg) * 4096;
#pragma unroll
  for (int n = 0; n < 4; ++n)
#pragma unroll
    for (int j = 0; j < 4; ++j) {
      const int p = w * 16 + lk * 4 + j;
      dst[p * 64 + n * 16 + lr] = (F16)hh[n][j];
    }
}

// ---------------- combine across segments (h_bnd over h_loc, in place) ----
__global__ __launch_bounds__(256) void combine_kernel(F16* __restrict__ HLOC,
                                                      const float* __restrict__ LA) {
  const int bh = blockIdx.x, tid = threadIdx.x;
  const int p = tid >> 2, n0 = (tid & 3) * 16;
  F16* base = HLOC + (size_t)bh * NSEG * 4096 + p * 64 + n0;
  const float* la = LA + (size_t)bh * SEQLEN_;
  union U16 { uint4 v[2]; F16 h[16]; };
  float r[16];
#pragma unroll
  for (int i = 0; i < 16; ++i) r[i] = 0.f;
  for (int k = 0; k < NSEG; ++k) {
    F16* slot = base + (size_t)k * 4096;
    U16 hl; hl.v[0] = *(const uint4*)slot; hl.v[1] = *((const uint4*)slot + 1);
    float P = __expf(la[k * SEGLEN + SEGLEN - 1]);
    U16 ob;
#pragma unroll
    for (int i = 0; i < 16; ++i) ob.h[i] = (F16)r[i];
    *(uint4*)slot = ob.v[0]; *((uint4*)slot + 1) = ob.v[1];   // h_bnd[k]
#pragma unroll
    for (int i = 0; i < 16; ++i) r[i] = fmaf(P, r[i], (float)hl.h[i]);
  }
}

// ---------------- boundary correction: y[t,p] += exp(la[t]) * C[t].h_bnd ----
__global__ __launch_bounds__(256) void corr_kernel(const F16* __restrict__ BCH,
                                                   const float* __restrict__ LA,
                                                   const F16* __restrict__ HLOC,
                                                   F16* __restrict__ XS) {
  __shared__ __align__(16) F16 Cd[128 * 72];
  __shared__ __align__(16) F16 Hb[64 * 72];
  const int seg = blockIdx.x, h = blockIdx.y, b = blockIdx.z;
  const int tid = threadIdx.x;
  const size_t tok0 = (size_t)b * SEQLEN_ + (size_t)seg * SEGLEN;
  const int bh = b * 32 + h;
  {
    int t = tid >> 1, half = tid & 1;
    float Dv = __expf(LA[(size_t)bh * SEQLEN_ + seg * SEGLEN + t]);
    const F16* src = BCH + (tok0 + t) * 128 + 64 + half * 32;
    F16* dstp = &Cd[t * 72 + half * 32];
#pragma unroll
    for (int i = 0; i < 4; ++i) {
      f16x8 cv = *(const f16x8*)(src + i * 8);
      f16x8 o;
#pragma unroll
      for (int q = 0; q < 8; ++q) o[q] = (F16)(Dv * (float)cv[q]);
      *(f16x8*)(dstp + i * 8) = o;
    }
  }
  {
    int p = tid >> 2, nn = (tid & 3) * 16;
    const F16* src = HLOC + ((size_t)bh * NSEG + seg) * 4096 + p * 64 + nn;
    uint4 a0 = *(const uint4*)src, a1 = *((const uint4*)src + 1);
    *(uint4*)&Hb[p * 72 + nn] = a0;
    *(uint4*)&Hb[p * 72 + nn + 8] = a1;
  }
  __syncthreads();
  const int lane = tid & 63, w = tid >> 6;
  const int lr = lane & 15, lk = lane >> 4;
  f32x4 acc[2][4];
#pragma unroll
  for (int m = 0; m < 2; ++m)
#pragma unroll
    for (int n = 0; n < 4; ++n) acc[m][n] = f32x4{0.f, 0.f, 0.f, 0.f};
#pragma unroll
  for (int kk = 0; kk < 2; ++kk) {
    f16x8 a0 = *(const f16x8*)&Cd[(w * 32 + lr) * 72 + kk * 32 + lk * 8];
    f16x8 a1 = *(const f16x8*)&Cd[(w * 32 + 16 + lr) * 72 + kk * 32 + lk * 8];
#pragma unroll
    for (int n = 0; n < 4; ++n) {
      f16x8 bq = *(const f16x8*)&Hb[(n * 16 + lr) * 72 + kk * 32 + lk * 8];
      acc[0][n] = __builtin_amdgcn_mfma_f32_16x16x32_f16(a0, bq, acc[0][n], 0, 0, 0);
      acc[1][n] = __builtin_amdgcn_mfma_f32_16x16x32_f16(a1, bq, acc[1][n], 0, 0, 0);
    }
  }
#pragma unroll
  for (int m = 0; m < 2; ++m)
#pragma unroll
    for (int n = 0; n < 4; ++n)
#pragma unroll
      for (int j = 0; j < 4; ++j) {
        int t = w * 32 + m * 16 + lk * 4 + j;
        int p = n * 16 + lr;
        F16* yp = XS + (tok0 + t) * 2048 + h * 64 + p;
        *yp = (F16)((float)*yp + acc[m][n][j]);
      }
}

// ---------------- y * silu(z) -> LN (2048) -> f16, in-place over Y ----------------
__global__ __launch_bounds__(256) void silu_ln_kernel(F16* __restrict__ Y,
                                                      const F16* __restrict__ Z,
                                                      const float* __restrict__ lnw,
                                                      const float* __restrict__ lnb) {
  int row = blockIdx.x, tid = threadIdx.x;
  size_t base = (size_t)row * DINNER + tid * 8;
  union { uint4 v; F16 h[8]; } yb, zb, ob;
  yb.v = *(const uint4*)(Y + base);
  zb.v = *(const uint4*)(Z + base);
  float vv[8];
  float s = 0.f, ss = 0.f;
#pragma unroll
  for (int i = 0; i < 8; ++i) {
    float y = (float)yb.h[i];
    float z = (float)zb.h[i];
    float sg = 1.f / (1.f + expf(-z));
    float v = y * z * sg;
    vv[i] = v; s += v; ss += v * v;
  }
  blk_reduce2(s, ss);
  float mu = s * (1.f / DINNER);
  float var = ss * (1.f / DINNER) - mu * mu;
  float rs = rsqrtf(var + 1e-5f);
#pragma unroll
  for (int i = 0; i < 8; ++i) {
    float w = lnw[tid * 8 + i], b = lnb[tid * 8 + i];
    ob.h[i] = (F16)((vv[i] - mu) * rs * w + b);
  }
  *(uint4*)(Y + base) = ob.v;
}

// ---------------- clip + final LN (1024): O1H f16 in -> f32 d_out ----------------
__global__ __launch_bounds__(256) void final_ln_kernel(const F16* __restrict__ O1H,
                                                       const float* __restrict__ w,
                                                       const float* __restrict__ b,
                                                       float* __restrict__ out) {
  int row = blockIdx.x, tid = threadIdx.x;
  size_t base = (size_t)row * DMODEL + tid * 4;
  f16x4 hv = *(const f16x4*)(O1H + base);
  float4 v = { (float)hv.x, (float)hv.y, (float)hv.z, (float)hv.w };
  v.x = fminf(fmaxf(v.x, -10.f), 10.f);
  v.y = fminf(fmaxf(v.y, -10.f), 10.f);
  v.z = fminf(fmaxf(v.z, -10.f), 10.f);
  v.w = fminf(fmaxf(v.w, -10.f), 10.f);
  float s = v.x + v.y + v.z + v.w;
  float ss = v.x * v.x + v.y * v.y + v.z * v.z + v.w * v.w;
  blk_reduce2(s, ss);
  float mu = s * (1.f / DMODEL);
  float var = ss * (1.f / DMODEL) - mu * mu;
  float rs = rsqrtf(var + 1e-5f);
  float4 wv = *(const float4*)(w + tid * 4);
  float4 bv = *(const float4*)(b + tid * 4);
  float4 o;
  o.x = (v.x - mu) * rs * wv.x + bv.x;
  o.y = (v.y - mu) * rs * wv.y + bv.y;
  o.z = (v.z - mu) * rs * wv.z + bv.z;
  o.w = (v.w - mu) * rs * wv.w + bv.w;
  *(float4*)(out + base) = o;
}

// ---------------- launcher ----------------
// Workspace high-water 117,440,512 B < proven-safe 119,865,344. Aliasing:
//   Z->d_out; y->XS in place; W2F->XN head; HLOC/LA->dead XN/W1F tail;
//   O1H (f16 gemm2 out) -> HLOC region (dead after corr). BCH (f16 B|C).
extern "C" void kernel_launch(void* const* d_in, const int* in_sizes, int n_in,
                              void* d_out, int out_size, void* d_ws, size_t ws_size,
                              hipStream_t stream) {
  const float* x       = (const float*)d_in[0];
  const float* w1      = (const float*)d_in[1];
  const float* w2      = (const float*)d_in[2];
  const float* A_log   = (const float*)d_in[3];
  const float* dt_bias = (const float*)d_in[4];
  const float* Dparam  = (const float*)d_in[5];
  const float* ln_w    = (const float*)d_in[6];
  const float* ln_b    = (const float*)d_in[7];
  const float* ni_w    = (const float*)d_in[8];
  const float* ni_b    = (const float*)d_in[9];
  const float* no_w    = (const float*)d_in[10];
  const float* no_b    = (const float*)d_in[11];

  const size_t NEEDED = 119865344ull;
  if (ws_size < NEEDED) return;

  char* wsb = (char*)d_ws;
  F16*   XS   = (F16*)  (wsb + 0ull);           // 16384x2048 f16 (x_ssm -> y -> y_gn)
  F16*   BCH  = (F16*)  (wsb + 67108864ull);    // 16384x128 f16 (B|C)
  float* DT   = (float*)(wsb + 75497472ull);    // 16384x32 f32 (raw dt)
  F16*   XN   = (F16*)  (wsb + 77594624ull);    // 16384x1024 f16 (dead after gemm1)
  F16*   W2F  = (F16*)  (wsb + 77594624ull);    // 1024x2048 f16 (reuses XN head)
  F16*   HLOC = (F16*)  (wsb + 81788928ull);    // 128x32x64x64 f16 = 32 MiB
  F16*   O1H  = (F16*)  (wsb + 81788928ull);    // 16384x1024 f16 (reuses HLOC after corr)
  float* LA   = (float*)(wsb + 115343360ull);   // 128x4096 f32 = 2 MiB
  F16*   W1F  = (F16*)  (wsb + 111149056ull);   // 4256x1024 f16 (dead after gemm1;
                                                // overlaps HLOC/LA tail — safe by ordering)

  F16*   Z   = (F16*)d_out;                     // 16384x2048 f16 in d_out (until silu_ln)

  cvt_kernel<<<4256, 256, 0, stream>>>(w1, W1F, (DINPRJ * DMODEL) / 4);
  ln_in_kernel<<<NTOK, 256, 0, stream>>>(x, ni_w, ni_b, XN);
  gemm_kernel<1024, 0><<<128 * 34, 256, 0, stream>>>(
      XN, W1F, DINPRJ, Z, XS, BCH, DT, nullptr);
  cvt_kernel<<<2048, 256, 0, stream>>>(w2, W2F, (DMODEL * DINNER) / 4);
  la_kernel<<<dim3(128, NSEG), 128, 0, stream>>>(DT, dt_bias, A_log, LA);
  ssd_kernel<<<dim3(32, NSEG, 4), 256, 0, stream>>>(BCH, LA, XS, Dparam, HLOC);
  combine_kernel<<<128, 256, 0, stream>>>(HLOC, LA);
  corr_kernel<<<dim3(NSEG, 32, 4), 256, 0, stream>>>(BCH, LA, HLOC, XS);
  silu_ln_kernel<<<NTOK, 256, 0, stream>>>(XS, Z, ln_w, ln_b);
  gemm_kernel<2048, 1><<<128 * 8, 256, 0, stream>>>(
      XS, W2F, 1024, nullptr, nullptr, nullptr, nullptr, O1H);
  final_ln_kernel<<<NTOK, 256, 0, stream>>>(O1H, no_w, no_b, (float*)d_out);
}